// Round 1
// baseline (356.320 us; speedup 1.0000x reference)
//
#include <hip/hip_runtime.h>
#include <hip/hip_bf16.h>
#include <math.h>

typedef unsigned short u16;
typedef __attribute__((ext_vector_type(8))) short bf16x8;
typedef __attribute__((ext_vector_type(4))) float f32x4;

#define S_LEN 2048
#define H_CNT 16
#define HDIM 64
#define D_MODEL 1024
#define M_ROWS 4096
#define N_QKV 3072

__device__ __forceinline__ u16 f2bf(float x) {
  unsigned u = __float_as_uint(x);
  unsigned r = u + 0x7FFF + ((u >> 16) & 1);
  return (u16)(r >> 16);
}
__device__ __forceinline__ float elu_f(float v) { return v > 0.f ? v : __expf(v) - 1.f; }

__device__ __forceinline__ void gload_lds16(const void* g, void* l) {
  __builtin_amdgcn_global_load_lds((const __attribute__((address_space(1))) void*)g,
                                   (__attribute__((address_space(3))) void*)l, 16, 0, 0);
}

// ---- x fp32 -> bf16, 8 elems/thread ----
__global__ __launch_bounds__(256) void k_cvt(const float* __restrict__ in, u16* __restrict__ out, int n8) {
  int i = blockIdx.x * 256 + threadIdx.x;
  if (i >= n8) return;
  const float4* v = (const float4*)in;
  float4 a = v[2 * i], b = v[2 * i + 1];
  float f[8] = {a.x, a.y, a.z, a.w, b.x, b.y, b.z, b.w};
  union { u16 us[8]; bf16x8 v8; } p;
#pragma unroll
  for (int j = 0; j < 8; ++j) p.us[j] = f2bf(f[j]);
  ((bf16x8*)out)[i] = p.v8;
}

// ---- transpose fp32 [K][N] -> bf16 [N][K] ----
__global__ __launch_bounds__(256) void k_transpose(const float* __restrict__ in, u16* __restrict__ out,
                                                   int K, int N) {
  __shared__ float tile[32][33];
  int nb = blockIdx.x * 32, kb = blockIdx.y * 32;
#pragma unroll
  for (int r = threadIdx.y; r < 32; r += 8)
    tile[r][threadIdx.x] = in[(size_t)(kb + r) * N + nb + threadIdx.x];
  __syncthreads();
#pragma unroll
  for (int r = threadIdx.y; r < 32; r += 8)
    out[(size_t)(nb + r) * K + kb + threadIdx.x] = f2bf(tile[threadIdx.x][r]);
}

// ---- bf16 GEMM: C[M][N] = A[M][K] * Bt[N][K]^T, 128x128 tile, BK=32 ----
// EPI 0: QKV epilogue (deinterleave stride-3 -> Q*0.125, K, elu(V) transposed)
// EPI 1: plain fp32 out + bias
template <int EPI>
__global__ __launch_bounds__(256) void k_gemm(const u16* __restrict__ A, const u16* __restrict__ Bt,
                                              int M, int N, int K, const float* __restrict__ bias,
                                              u16* __restrict__ Qb, u16* __restrict__ Kb,
                                              u16* __restrict__ Vt, float* __restrict__ Co) {
  __shared__ __align__(16) u16 sA[128 * 32];
  __shared__ __align__(16) u16 sB[128 * 32];
  const int t = threadIdx.x;
  const int lane = t & 63, wave = t >> 6;
  const int wm = wave >> 1, wn = wave & 1;
  const int row0 = blockIdx.x * 128, col0 = blockIdx.y * 128;

  const int sr = wave * 16 + (lane >> 2);
  const int scb = (lane & 3) * 16;
  const char* gA0 = (const char*)(A + (size_t)(row0 + sr) * K) + scb;
  const char* gA1 = gA0 + (size_t)64 * K * 2;
  const char* gB0 = (const char*)(Bt + (size_t)(col0 + sr) * K) + scb;
  const char* gB1 = gB0 + (size_t)64 * K * 2;
  u16* lA0 = sA + wave * 512;
  u16* lA1 = sA + 2048 + wave * 512;
  u16* lB0 = sB + wave * 512;
  u16* lB1 = sB + 2048 + wave * 512;

  f32x4 acc[4][4] = {};

  const int nks = K >> 5;
  for (int ks = 0; ks < nks; ++ks) {
    const size_t kb = (size_t)ks * 64;  // bytes along K
    gload_lds16(gA0 + kb, lA0);
    gload_lds16(gA1 + kb, lA1);
    gload_lds16(gB0 + kb, lB0);
    gload_lds16(gB1 + kb, lB1);
    __syncthreads();
    bf16x8 af[4], bfr[4];
#pragma unroll
    for (int i = 0; i < 4; ++i) {
      af[i] = *(const bf16x8*)&sA[(wm * 64 + i * 16 + (lane & 15)) * 32 + (lane >> 4) * 8];
      bfr[i] = *(const bf16x8*)&sB[(wn * 64 + i * 16 + (lane & 15)) * 32 + (lane >> 4) * 8];
    }
#pragma unroll
    for (int mi = 0; mi < 4; ++mi)
#pragma unroll
      for (int ni = 0; ni < 4; ++ni)
        acc[mi][ni] = __builtin_amdgcn_mfma_f32_16x16x32_bf16(af[mi], bfr[ni], acc[mi][ni], 0, 0, 0);
    __syncthreads();
  }

#pragma unroll
  for (int mi = 0; mi < 4; ++mi) {
    const int rbase = row0 + wm * 64 + mi * 16 + (lane >> 4) * 4;
#pragma unroll
    for (int ni = 0; ni < 4; ++ni) {
      const int c = col0 + wn * 64 + ni * 16 + (lane & 15);
#pragma unroll
      for (int r = 0; r < 4; ++r) {
        const int m = rbase + r;
        float v = acc[mi][ni][r] + bias[c];
        if (EPI == 0) {
          const int d = c / 3, j = c - d * 3;
          const int h = d >> 6, hd = d & 63;
          const int b = m >> 11, s = m & 2047;
          const size_t bh = (size_t)(b * H_CNT + h);
          if (j == 0)
            Qb[(bh * S_LEN + s) * HDIM + hd] = f2bf(v * 0.125f);
          else if (j == 1)
            Kb[(bh * S_LEN + s) * HDIM + hd] = f2bf(v);
          else
            Vt[(bh * HDIM + hd) * S_LEN + s] = f2bf(elu_f(v));
        } else {
          Co[(size_t)m * N + c] = v;
        }
      }
    }
  }
}

// ---- flash attention: 4 waves/block, 16 q-rows/wave, kv-step 32 ----
__global__ __launch_bounds__(256) void k_attn(const u16* __restrict__ Qb, const u16* __restrict__ Kb,
                                              const u16* __restrict__ Vt, const float* __restrict__ mask,
                                              u16* __restrict__ Ob) {
  __shared__ __align__(16) u16 pl[4][16][32];
  const int t = threadIdx.x, lane = t & 63, wave = t >> 6;
  const int qt = blockIdx.x, bh = blockIdx.y;
  const int b = bh >> 4, h = bh & 15;
  const u16* Qp = Qb + (size_t)bh * S_LEN * HDIM;
  const u16* Kp = Kb + (size_t)bh * S_LEN * HDIM;
  const u16* Vp = Vt + (size_t)bh * HDIM * S_LEN;
  const float* mp = mask + (size_t)b * S_LEN;

  const int qrow = qt * 64 + wave * 16 + (lane & 15);
  bf16x8 qf[2];
  qf[0] = *(const bf16x8*)&Qp[(size_t)qrow * HDIM + (lane >> 4) * 8];
  qf[1] = *(const bf16x8*)&Qp[(size_t)qrow * HDIM + 32 + (lane >> 4) * 8];

  f32x4 o[4] = {};
  float mrow[4] = {-INFINITY, -INFINITY, -INFINITY, -INFINITY};
  float lrow[4] = {};

  for (int kv = 0; kv < S_LEN; kv += 32) {
    f32x4 sacc[2] = {};
#pragma unroll
    for (int nf = 0; nf < 2; ++nf) {
      const int key = kv + nf * 16 + (lane & 15);
#pragma unroll
      for (int kk = 0; kk < 2; ++kk) {
        bf16x8 kf = *(const bf16x8*)&Kp[(size_t)key * HDIM + kk * 32 + (lane >> 4) * 8];
        sacc[nf] = __builtin_amdgcn_mfma_f32_16x16x32_bf16(qf[kk], kf, sacc[nf], 0, 0, 0);
      }
    }
    const float mk0 = mp[kv + (lane & 15)];
    const float mk1 = mp[kv + 16 + (lane & 15)];
    float mx[4], p0[4], p1[4], ps[4];
#pragma unroll
    for (int r = 0; r < 4; ++r) {
      sacc[0][r] += mk0;
      sacc[1][r] += mk1;
      mx[r] = fmaxf(sacc[0][r], sacc[1][r]);
    }
#pragma unroll
    for (int r = 0; r < 4; ++r) {
      mx[r] = fmaxf(mx[r], __shfl_xor(mx[r], 1));
      mx[r] = fmaxf(mx[r], __shfl_xor(mx[r], 2));
      mx[r] = fmaxf(mx[r], __shfl_xor(mx[r], 4));
      mx[r] = fmaxf(mx[r], __shfl_xor(mx[r], 8));
    }
#pragma unroll
    for (int r = 0; r < 4; ++r) {
      float mn = fmaxf(mrow[r], mx[r]);
      float sc = __expf(mrow[r] - mn);
      mrow[r] = mn;
      lrow[r] *= sc;
      o[0][r] *= sc; o[1][r] *= sc; o[2][r] *= sc; o[3][r] *= sc;
      p0[r] = __expf(sacc[0][r] - mn);
      p1[r] = __expf(sacc[1][r] - mn);
      ps[r] = p0[r] + p1[r];
    }
#pragma unroll
    for (int r = 0; r < 4; ++r) {
      ps[r] += __shfl_xor(ps[r], 1);
      ps[r] += __shfl_xor(ps[r], 2);
      ps[r] += __shfl_xor(ps[r], 4);
      ps[r] += __shfl_xor(ps[r], 8);
      lrow[r] += ps[r];
    }
#pragma unroll
    for (int r = 0; r < 4; ++r) {
      pl[wave][(lane >> 4) * 4 + r][lane & 15] = f2bf(p0[r]);
      pl[wave][(lane >> 4) * 4 + r][16 + (lane & 15)] = f2bf(p1[r]);
    }
    bf16x8 pa = *(const bf16x8*)&pl[wave][lane & 15][(lane >> 4) * 8];
#pragma unroll
    for (int nf = 0; nf < 4; ++nf) {
      bf16x8 vf = *(const bf16x8*)&Vp[(size_t)(nf * 16 + (lane & 15)) * S_LEN + kv + (lane >> 4) * 8];
      o[nf] = __builtin_amdgcn_mfma_f32_16x16x32_bf16(pa, vf, o[nf], 0, 0, 0);
    }
  }

  const int orow = b * S_LEN + qt * 64 + wave * 16 + (lane >> 4) * 4;
#pragma unroll
  for (int r = 0; r < 4; ++r) {
    float inv = 1.f / lrow[r];
    const size_t base = (size_t)(orow + r) * D_MODEL + h * HDIM + (lane & 15);
#pragma unroll
    for (int nf = 0; nf < 4; ++nf) Ob[base + nf * 16] = f2bf(o[nf][r] * inv);
  }
}

// ---- fused LayerNorm + ELU + residual, in-place on d_out ----
__global__ __launch_bounds__(256) void k_ln(float* __restrict__ po, const float* __restrict__ x,
                                            const float* __restrict__ g, const float* __restrict__ bb) {
  const int row = blockIdx.x, t = threadIdx.x;
  float4 v = ((const float4*)(po + (size_t)row * D_MODEL))[t];
  float s = v.x + v.y + v.z + v.w;
  float s2 = v.x * v.x + v.y * v.y + v.z * v.z + v.w * v.w;
#pragma unroll
  for (int m = 1; m < 64; m <<= 1) {
    s += __shfl_xor(s, m);
    s2 += __shfl_xor(s2, m);
  }
  __shared__ float rs[4], rs2[4];
  if ((t & 63) == 0) {
    rs[t >> 6] = s;
    rs2[t >> 6] = s2;
  }
  __syncthreads();
  s = rs[0] + rs[1] + rs[2] + rs[3];
  s2 = rs2[0] + rs2[1] + rs2[2] + rs2[3];
  const float mean = s * (1.f / 1024.f);
  const float var = s2 * (1.f / 1024.f) - mean * mean;
  const float rstd = rsqrtf(var + 1e-5f);
  float4 xg = ((const float4*)(x + (size_t)row * D_MODEL))[t];
  float4 gg = ((const float4*)g)[t];
  float4 bv = ((const float4*)bb)[t];
  float4 o;
  o.x = elu_f((v.x - mean) * rstd * gg.x + bv.x) + xg.x;
  o.y = elu_f((v.y - mean) * rstd * gg.y + bv.y) + xg.y;
  o.z = elu_f((v.z - mean) * rstd * gg.z + bv.z) + xg.z;
  o.w = elu_f((v.w - mean) * rstd * gg.w + bv.w) + xg.w;
  ((float4*)(po + (size_t)row * D_MODEL))[t] = o;
}

extern "C" void kernel_launch(void* const* d_in, const int* in_sizes, int n_in, void* d_out,
                              int out_size, void* d_ws, size_t ws_size, hipStream_t stream) {
  const float* x = (const float*)d_in[0];
  const float* mask = (const float*)d_in[1];
  const float* w_qkv = (const float*)d_in[2];
  const float* b_qkv = (const float*)d_in[3];
  const float* w_out = (const float*)d_in[4];
  const float* b_out = (const float*)d_in[5];
  const float* ln_g = (const float*)d_in[6];
  const float* ln_b = (const float*)d_in[7];
  float* out = (float*)d_out;

  char* ws = (char*)d_ws;
  u16* xb = (u16*)(ws);                          // 8 MiB: [4096][1024] bf16
  u16* wqkvT = (u16*)(ws + (8ull << 20));        // 6 MiB: [3072][1024]
  u16* woutT = (u16*)(ws + (14ull << 20));       // 2 MiB: [1024][1024]
  u16* Qb = (u16*)(ws + (16ull << 20));          // 8 MiB: [32 bh][2048][64]
  u16* Kb = (u16*)(ws + (24ull << 20));          // 8 MiB
  u16* Vt = (u16*)(ws + (32ull << 20));          // 8 MiB: [32 bh][64][2048]
  u16* Ob = (u16*)(ws + (40ull << 20));          // 8 MiB: [4096][1024]

  k_cvt<<<2048, 256, 0, stream>>>(x, xb, (M_ROWS * D_MODEL) / 8);
  dim3 tb(32, 8);
  k_transpose<<<dim3(N_QKV / 32, D_MODEL / 32), tb, 0, stream>>>(w_qkv, wqkvT, D_MODEL, N_QKV);
  k_transpose<<<dim3(D_MODEL / 32, D_MODEL / 32), tb, 0, stream>>>(w_out, woutT, D_MODEL, D_MODEL);
  k_gemm<0><<<dim3(M_ROWS / 128, N_QKV / 128), 256, 0, stream>>>(xb, wqkvT, M_ROWS, N_QKV, D_MODEL,
                                                                 b_qkv, Qb, Kb, Vt, nullptr);
  k_attn<<<dim3(S_LEN / 64, 32), 256, 0, stream>>>(Qb, Kb, Vt, mask, Ob);
  k_gemm<1><<<dim3(M_ROWS / 128, D_MODEL / 128), 256, 0, stream>>>(Ob, woutT, M_ROWS, D_MODEL, D_MODEL,
                                                                   b_out, nullptr, nullptr, nullptr, out);
  k_ln<<<M_ROWS, 256, 0, stream>>>(out, x, ln_g, ln_b);
}